// Round 10
// baseline (532.675 us; speedup 1.0000x reference)
//
#include <hip/hip_runtime.h>

// Fused NeRF-MLP. Round 10: OCCUPANCY without spill (single-variable vs R8).
// MT 64->32, wave tile 64ch x 32rows -> acc[4][2] = 32 VGPR; launch_bounds
// (256,4) -> VGPR cap 128 (no spill, ~90 needed); LDS 34.6KB -> 4 blocks/CU
// = 4 waves/SIMD (2x R8/R9). Structure otherwise identical to R8: glds
// B-ring (4x4KB, depth-3, counted vmcnt), direct-L2 weights in LHALF,
// AfG[3] distance-2 in GHALF, in-register heads.
// 8192 blocks x 256 thr (4 waves), 32 rows/block.

typedef __bf16 bf16x8 __attribute__((ext_vector_type(8)));
typedef float  f32x4  __attribute__((ext_vector_type(4)));
typedef short  short8 __attribute__((ext_vector_type(8)));
typedef unsigned int uint4v __attribute__((ext_vector_type(4)));

#define NROWS (8192 * 32)
#define MT 32
#define RS 260   // act row stride (520B; measured 0 LDS conflicts in R7)

// packed-weight layout (bf16 elems): kt chunks of 8192 elems, lane-linear.
#define P0B   0        // W0^T  K=64 (pad 63)  : 2 kt
#define P1B   16384    // W1    K=256          : 8 kt
#define P2B   81920    // W2    K=512          : 16 kt
#define P3B   212992   // W3    K=512          : 16 kt
#define P4AB  344064   // W4[:256]   K=256     : 8 kt
#define P4BB  409600   // W4[256:283] K=32(27) : 1 kt
#define PTOT  417792

#define ACT_ELEMS (MT * RS)                       // 8320 ushorts = 16640 B
// act 16640 + ring 4*4096 + scr 1536 = 34560 B -> 4 blocks/CU
#define SMEM_BYTES (ACT_ELEMS * 2 + 4 * 4096 + 1536)

__device__ __forceinline__ unsigned short f2bf(float f) {
  unsigned u = __builtin_bit_cast(unsigned, f);
  u += 0x7fffu + ((u >> 16) & 1u);   // RNE
  return (unsigned short)(u >> 16);
}
__device__ __forceinline__ unsigned cvt_pk(float lo, float hi) {
  unsigned r;
  asm("v_cvt_pk_bf16_f32 %0, %1, %2" : "=v"(r) : "v"(lo), "v"(hi));
  return r;
}
__device__ __forceinline__ bf16x8 cvt8(f32x4 x, f32x4 y) {
  uint4v u;
  u[0] = cvt_pk(x[0], x[1]); u[1] = cvt_pk(x[2], x[3]);
  u[2] = cvt_pk(y[0], y[1]); u[3] = cvt_pk(y[2], y[3]);
  return __builtin_bit_cast(bf16x8, u);
}
__device__ __forceinline__ bf16x8 as_bf(short8 s) {
  return __builtin_bit_cast(bf16x8, s);
}

#define SB __builtin_amdgcn_sched_barrier(0)

#define GLDS16(gsrc, ldst)                                                     \
  __builtin_amdgcn_global_load_lds(                                            \
      (const __attribute__((address_space(1))) unsigned int*)(gsrc),           \
      (__attribute__((address_space(3))) unsigned int*)(ldst), 16, 0, 0)

// ---------------- pre-pass: pack weights to fragment layout -----------------
// chunk(kt) elem bits: wv[12:11] ct[10:9] seg[8:7] l16[6:3] j[2:0]
// holds W[kt*32 + seg*8 + j][wv*64 + ct*16 + l16]
__global__ void prep_pack(const float* __restrict__ W0, const float* __restrict__ W1,
                          const float* __restrict__ W2, const float* __restrict__ W3,
                          const float* __restrict__ W4, const float* __restrict__ Wr,
                          const float* __restrict__ app, const float* __restrict__ b4,
                          unsigned short* __restrict__ pack, float* __restrict__ b4p,
                          float* __restrict__ wrT)
{
  int gid = blockIdx.x * 256 + threadIdx.x;
  if (gid < PTOT) {
    const float* W; int Kreal, base, krow = 0;
    if      (gid < P1B)  { W = W0; Kreal = 63;  base = P0B; }
    else if (gid < P2B)  { W = W1; Kreal = 256; base = P1B; }
    else if (gid < P3B)  { W = W2; Kreal = 512; base = P2B; }
    else if (gid < P4AB) { W = W3; Kreal = 512; base = P3B; }
    else if (gid < P4BB) { W = W4; Kreal = 256; base = P4AB; }
    else                 { W = W4; Kreal = 27;  base = P4BB; krow = 256; }
    int local = gid - base;
    int j   = local & 7;
    int l16 = (local >> 3) & 15;
    int seg = (local >> 7) & 3;
    int ct  = (local >> 9) & 3;
    int wv  = (local >> 11) & 3;
    int kt  = local >> 13;
    int o = wv * 64 + ct * 16 + l16;
    int k = kt * 32 + seg * 8 + j;
    float v = (k < Kreal) ? W[(long)(k + krow) * 256 + o] : 0.f;
    pack[gid] = f2bf(v);
  } else if (gid < PTOT + 256) {
    int o = gid - PTOT;
    float a = b4[o];
    for (int i = 0; i < 48; ++i) a += app[i] * W4[(long)(283 + i) * 256 + o];
    b4p[o] = a;
  } else if (gid < PTOT + 256 + 768) {
    int idx = gid - (PTOT + 256);
    int c = idx >> 8, ch = idx & 255;
    wrT[c * 256 + ch] = Wr[ch * 3 + c];
  }
}

// ---------------- main fused kernel ----------------------------------------
__global__ __launch_bounds__(256, 4)
void nerf_fused(const float* __restrict__ pos, const float* __restrict__ dirs,
                const float* __restrict__ gemo, const float* __restrict__ color,
                const float* __restrict__ mask,
                const unsigned short* __restrict__ wp,
                const float* __restrict__ b0, const float* __restrict__ b1,
                const float* __restrict__ b2, const float* __restrict__ bsv,
                const float* __restrict__ b3, const float* __restrict__ b4p,
                const float* __restrict__ brv,
                const float* __restrict__ Wsf, const float* __restrict__ wrT,
                float* __restrict__ osig, float* __restrict__ orgb)
{
  extern __shared__ unsigned short smem[];
  unsigned short* act  = smem;                       // [32][RS] bf16
  unsigned short* ring = smem + ACT_ELEMS;           // 4 slots x 4KB raw f32
  float* scr = (float*)(smem + ACT_ELEMS + 4 * 2048);  // 1.5 KB head scratch

  const int tid  = (int)threadIdx.x;
  const int w    = tid >> 6;
  const int lane = tid & 63;
  const int l16  = lane & 15;
  const int seg  = lane >> 4;
  const int chb  = w * 64;              // 4 disjoint 64-ch slices
  const long R0  = (long)blockIdx.x * MT;
  const int rot  = (int)(blockIdx.x & 7);

  f32x4 acc[4][2];

  // stage one 4KB B-chunk (32 rows x 32 f32 cols): 1 glds per thread.
  // unit u = tid holds (row=u>>3, part=(u&7)^(row&7)) -> swizzled b128 reads.
  auto stageB = [&](const float* __restrict__ P, int slot, int c) {
    int u = tid;
    int row = u >> 3;
    int part = (u & 7) ^ (row & 7);
    const float* src = P + (R0 + row) * 256 + c * 32 + part * 4;
    unsigned short* dst = ring + slot * 2048 + u * 8;
    GLDS16(src, dst);
  };
  auto ldB_ring = [&](int slot, int rt, int p) -> f32x4 {
    int row = rt * 16 + l16;
    return *(const f32x4*)(ring + slot * 2048 + (row * 8 + (p ^ (row & 7))) * 8);
  };
  auto ldAd = [&](int baseElems, int kt, int ct) -> bf16x8 {
    return *(const bf16x8*)(wp + baseElems + kt * 8192 + w * 2048 +
                            ((ct * 4 + seg) * 16 + l16) * 8);
  };
  auto ldB_act = [&](int rt, int kt) -> bf16x8 {
    int row = rt * 16 + l16;
    return *(const bf16x8*)(act + row * RS + kt * 32 + seg * 8);
  };
  auto ldB_gen = [&](const float* __restrict__ p, int stride, int Kreal,
                     int rt, int ktl) -> bf16x8 {
    long row = R0 + rt * 16 + l16;
    const float* q = p + row * stride;
    int k0 = ktl * 32 + seg * 8;
    short8 s;
#pragma unroll
    for (int j = 0; j < 8; ++j) {
      float v = (k0 + j < Kreal) ? __builtin_nontemporal_load(q + k0 + j) : 0.0f;
      s[j] = (short)f2bf(v);
    }
    return as_bf(s);
  };
  auto initAcc = [&](const float* __restrict__ b) {
#pragma unroll
    for (int ct = 0; ct < 4; ++ct) {
      float4 bv = *(const float4*)(b + chb + ct * 16 + seg * 4);
      f32x4 t; t[0] = bv.x; t[1] = bv.y; t[2] = bv.z; t[3] = bv.w;
#pragma unroll
      for (int rt = 0; rt < 2; ++rt) acc[ct][rt] = t;
    }
  };
  auto storeAct = [&]() {
#pragma unroll
    for (int ct = 0; ct < 4; ++ct)
#pragma unroll
      for (int rt = 0; rt < 2; ++rt) {
        int row = rt * 16 + l16;
        int ch  = chb + ct * 16 + seg * 4;
        f32x4 v = acc[ct][rt];
        uint2 u;
        u.x = cvt_pk(fmaxf(v[0], 0.f), fmaxf(v[1], 0.f));
        u.y = cvt_pk(fmaxf(v[2], 0.f), fmaxf(v[3], 0.f));
        *(uint2*)(act + row * RS + ch) = u;
      }
  };

#define MFMA8(AFRAG, BFRAGS)                                                   \
  _Pragma("unroll") for (int ct = 0; ct < 4; ++ct) {                           \
    _Pragma("unroll") for (int rt = 0; rt < 2; ++rt)                           \
      acc[ct][rt] = __builtin_amdgcn_mfma_f32_16x16x32_bf16(                   \
          AFRAG[ct], BFRAGS[rt], acc[ct][rt], 0, 0, 0);                        \
  }

// 8 K-steps, B from act LDS, A direct L2 (compiler-scheduled).
#define LHALF(ABASE)                                                           \
  _Pragma("unroll") for (int i = 0; i < 8; ++i) {                              \
    int kt = (i + rot) & 7;                                                    \
    bf16x8 Bf_[2];                                                             \
    _Pragma("unroll") for (int rt = 0; rt < 2; ++rt) Bf_[rt] = ldB_act(rt, kt); \
    bf16x8 Af_[4];                                                             \
    _Pragma("unroll") for (int ct = 0; ct < 4; ++ct) Af_[ct] = ldAd(ABASE, kt, ct); \
    MFMA8(Af_, Bf_);                                                           \
  }

// One stream step: [FENCE(N)][bar][A(i+2)->AfG][stage(i+3)][consume chunk i].
// Ledger (A=4 ops, stage=1 op): after st(i): G(i-2)[A(i),st(i+1)]=5 +
// G(i-1)[A(i+1),st(i+2)]=5 -> FENCE(10); tail: G6=9, G7=4.
#define GREG(i, NF)                                                            \
  {                                                                            \
    asm volatile("s_waitcnt vmcnt(" #NF ")" ::: "memory"); SB;                 \
    __builtin_amdgcn_s_barrier(); SB;                                          \
    if ((i) + 2 < 8) {                                                         \
      _Pragma("unroll") for (int ct = 0; ct < 4; ++ct)                         \
        AfG[((i) + 2) % 3][ct] = ldAd(GABASE, 8 + (((i) + 2 + rot) & 7), ct);  \
    }                                                                          \
    if ((i) + 3 < 8) stageB(GP, ((i) + 3) & 3, ((i) + 3 + rot) & 7);           \
    SB;                                                                        \
    bf16x8 Bf_[2];                                                             \
    _Pragma("unroll") for (int rt = 0; rt < 2; ++rt) {                         \
      f32x4 lo = ldB_ring((i) & 3, rt, 2 * seg);                               \
      f32x4 hi = ldB_ring((i) & 3, rt, 2 * seg + 1);                           \
      Bf_[rt] = cvt8(lo, hi);                                                  \
    }                                                                          \
    MFMA8(AfG[(i) % 3], Bf_);                                                  \
  }

#define GHALF(ABASE, P)                                                        \
  {                                                                            \
    const int GABASE = (ABASE); const float* __restrict__ GP = (P);            \
    bf16x8 AfG[3][4];                                                          \
    SB;                                                                        \
    _Pragma("unroll") for (int ct = 0; ct < 4; ++ct) {                         \
      AfG[0][ct] = ldAd(GABASE, 8 + ((0 + rot) & 7), ct);                      \
      AfG[1][ct] = ldAd(GABASE, 8 + ((1 + rot) & 7), ct);                      \
    }                                                                          \
    SB;                                                                        \
    GREG(0, 10) GREG(1, 10) GREG(2, 10) GREG(3, 10)                            \
    GREG(4, 10) GREG(5, 10) GREG(6, 9)  GREG(7, 4)                             \
  }

  // ---- L0: d0 = relu(pos @ W0 + b0) -> act
  initAcc(b0);
#pragma unroll
  for (int kt = 0; kt < 2; ++kt) {
    bf16x8 Bf_[2];
#pragma unroll
    for (int rt = 0; rt < 2; ++rt) Bf_[rt] = ldB_gen(pos, 63, 63, rt, kt);
    bf16x8 Af_[4];
#pragma unroll
    for (int ct = 0; ct < 4; ++ct) Af_[ct] = ldAd(P0B, kt, ct);
    MFMA8(Af_, Bf_);
  }
  storeAct();
  __syncthreads();

  // ---- L1: d1 = relu(d0 @ W1 + b1); act: d0 -> d1
  initAcc(b1);
  LHALF(P1B);
  __syncthreads();
  storeAct();
  __syncthreads();

  // ---- L2: d2 = [d1|gemo] @ W2 + b2 (stays in acc)
  // ring prolog first: gemo chunks 0..2 fly during LHALF's 8 steps
  stageB(gemo, 0, rot);
  stageB(gemo, 1, (1 + rot) & 7);
  stageB(gemo, 2, (2 + rot) & 7);
  initAcc(b2);
  LHALF(P2B);
  GHALF(P2B, gemo);

  // ---- sigma head (in-register): softplus(relu(d2) @ Ws + bs) * mask
  {
    float p[2];
#pragma unroll
    for (int rt = 0; rt < 2; ++rt) {
      float s = 0.f;
#pragma unroll
      for (int ct = 0; ct < 4; ++ct) {
        float4 w4 = *(const float4*)(Wsf + chb + ct * 16 + seg * 4);
        f32x4 a = acc[ct][rt];
        s += fmaxf(a[0], 0.f) * w4.x + fmaxf(a[1], 0.f) * w4.y +
             fmaxf(a[2], 0.f) * w4.z + fmaxf(a[3], 0.f) * w4.w;
      }
      s += __shfl_xor(s, 16);
      s += __shfl_xor(s, 32);
      p[rt] = s;
    }
    if (seg == 0) {
#pragma unroll
      for (int rt = 0; rt < 2; ++rt) scr[w * 32 + rt * 16 + l16] = p[rt];
    }
  }
  __syncthreads();
  if (tid < 32) {
    float s = scr[tid] + scr[32 + tid] + scr[64 + tid] + scr[96 + tid] + bsv[0];
    float sp = fmaxf(s, 0.f) + log1pf(expf(-fabsf(s)));
    float m = __builtin_nontemporal_load(mask + R0 + tid);
    __builtin_nontemporal_store(sp * m, osig + R0 + tid);
  }

  // ---- L3: d3 = relu([d1|color] @ W3 + b3); act: d1 -> d3
  stageB(color, 0, rot);
  stageB(color, 1, (1 + rot) & 7);
  stageB(color, 2, (2 + rot) & 7);
  initAcc(b3);
  LHALF(P3B);
  GHALF(P3B, color);
  __syncthreads();
  storeAct();
  __syncthreads();

  // ---- L4: d4 = [d3|dir|app] @ W4 + b4' (stays in acc)
  initAcc(b4p);
  LHALF(P4AB);
  {  // dir step (K=32, direct A)
    bf16x8 Bf_[2];
#pragma unroll
    for (int rt = 0; rt < 2; ++rt) Bf_[rt] = ldB_gen(dirs, 27, 27, rt, 0);
    bf16x8 Af_[4];
#pragma unroll
    for (int ct = 0; ct < 4; ++ct) Af_[ct] = ldAd(P4BB, 0, ct);
    MFMA8(Af_, Bf_);
  }

  // ---- rgb head (in-register): sigmoid(relu(d4) @ Wr + br)
  {
#pragma unroll
    for (int ct = 0; ct < 4; ++ct)
#pragma unroll
      for (int rt = 0; rt < 2; ++rt) {
        f32x4 a = acc[ct][rt];
        a[0] = fmaxf(a[0], 0.f); a[1] = fmaxf(a[1], 0.f);
        a[2] = fmaxf(a[2], 0.f); a[3] = fmaxf(a[3], 0.f);
        acc[ct][rt] = a;
      }
#pragma unroll
    for (int c = 0; c < 3; ++c) {
      float p[2];
#pragma unroll
      for (int rt = 0; rt < 2; ++rt) {
        float s = 0.f;
#pragma unroll
        for (int ct = 0; ct < 4; ++ct) {
          float4 w4 = *(const float4*)(wrT + c * 256 + chb + ct * 16 + seg * 4);
          f32x4 a = acc[ct][rt];
          s += a[0] * w4.x + a[1] * w4.y + a[2] * w4.z + a[3] * w4.w;
        }
        s += __shfl_xor(s, 16);
        s += __shfl_xor(s, 32);
        p[rt] = s;
      }
      if (seg == 0) {
#pragma unroll
        for (int rt = 0; rt < 2; ++rt)
          scr[c * 128 + w * 32 + rt * 16 + l16] = p[rt];
      }
    }
  }
  __syncthreads();
  if (tid < 32) {
#pragma unroll
    for (int c = 0; c < 3; ++c) {
      float s = scr[c * 128 + tid] + scr[c * 128 + 32 + tid] +
                scr[c * 128 + 64 + tid] + scr[c * 128 + 96 + tid] + brv[c];
      float r = 1.f / (1.f + expf(-s));
      __builtin_nontemporal_store(r, orgb + (R0 + tid) * 3 + c);
    }
  }
#undef MFMA8
#undef LHALF
#undef GREG
#undef GHALF
}

extern "C" void kernel_launch(void* const* d_in, const int* in_sizes, int n_in,
                              void* d_out, int out_size, void* d_ws, size_t ws_size,
                              hipStream_t stream) {
  const float* pos   = (const float*)d_in[0];
  const float* dirs  = (const float*)d_in[1];
  const float* app   = (const float*)d_in[2];
  const float* gemo  = (const float*)d_in[3];
  const float* color = (const float*)d_in[4];
  const float* mask  = (const float*)d_in[5];
  // d_in[6] = num_inters (fixed 32, shapes are static)
  const float* W0 = (const float*)d_in[7];   const float* b0 = (const float*)d_in[8];
  const float* W1 = (const float*)d_in[9];   const float* b1 = (const float*)d_in[10];
  const float* W2 = (const float*)d_in[11];  const float* b2 = (const float*)d_in[12];
  const float* Ws = (const float*)d_in[13];  const float* bs = (const float*)d_in[14];
  const float* W3 = (const float*)d_in[15];  const float* b3 = (const float*)d_in[16];
  const float* W4 = (const float*)d_in[17];  const float* b4 = (const float*)d_in[18];
  const float* Wr = (const float*)d_in[19];  const float* br = (const float*)d_in[20];

  unsigned short* pack = (unsigned short*)d_ws;
  float* b4p = (float*)((char*)d_ws + (size_t)PTOT * 2);
  float* wrT = b4p + 256;

  float* osig = (float*)d_out;
  float* orgb = osig + NROWS;

  prep_pack<<<dim3((PTOT + 256 + 768 + 255) / 256), dim3(256), 0, stream>>>(
      W0, W1, W2, W3, W4, Wr, app, b4, pack, b4p, wrT);

  hipFuncSetAttribute((const void*)nerf_fused,
                      hipFuncAttributeMaxDynamicSharedMemorySize, SMEM_BYTES);

  nerf_fused<<<dim3(NROWS / MT), dim3(256), SMEM_BYTES, stream>>>(
      pos, dirs, gemo, color, mask, pack,
      b0, b1, b2, bs, b3, b4p, br, Ws, wrT, osig, orgb);
}

// Round 11
// 472.397 us; speedup vs baseline: 1.1276x; 1.1276x over previous
//
#include <hip/hip_runtime.h>

// Fused NeRF-MLP. Round 11: R8's proven structure + 3 blocks/CU (LDS diet).
// m97-model: per-step MFMA/latency ratio fixed => MfmaUtil scales with
// waves/SIMD; R8 ran 2 (17.7%), m97 runs 3 (37%). LDS 69->52.7KB:
// B-ring 4->2 slots (stage c(i+1) after step-i barrier; prolog c0 gets a
// full LHALF of lead), AfG depth 2 (VGPR<=128 for the 12-waves/CU tier).
// 4096 blocks x 256 thr (4 waves), 64 rows/block, wave = 64ch x 64rows.

typedef __bf16 bf16x8 __attribute__((ext_vector_type(8)));
typedef float  f32x4  __attribute__((ext_vector_type(4)));
typedef short  short8 __attribute__((ext_vector_type(8)));
typedef unsigned int uint4v __attribute__((ext_vector_type(4)));

#define NROWS (8192 * 32)
#define MT 64
#define RS 260   // act row stride (520B; measured 0 LDS conflicts in R7)

// packed-weight layout (bf16 elems): kt chunks of 8192 elems, lane-linear.
#define P0B   0        // W0^T  K=64 (pad 63)  : 2 kt
#define P1B   16384    // W1    K=256          : 8 kt
#define P2B   81920    // W2    K=512          : 16 kt
#define P3B   212992   // W3    K=512          : 16 kt
#define P4AB  344064   // W4[:256]   K=256     : 8 kt
#define P4BB  409600   // W4[256:283] K=32(27) : 1 kt
#define PTOT  417792

#define ACT_ELEMS (MT * RS)                     // 16640 ushorts = 33280 B
// act 33280 + ring 2*8192 + scr 3072 = 52736 B -> 3 blocks/CU (x3 = 158208)
#define SMEM_BYTES (ACT_ELEMS * 2 + 2 * 8192 + 3072)

__device__ __forceinline__ unsigned short f2bf(float f) {
  unsigned u = __builtin_bit_cast(unsigned, f);
  u += 0x7fffu + ((u >> 16) & 1u);   // RNE
  return (unsigned short)(u >> 16);
}
__device__ __forceinline__ unsigned cvt_pk(float lo, float hi) {
  unsigned r;
  asm("v_cvt_pk_bf16_f32 %0, %1, %2" : "=v"(r) : "v"(lo), "v"(hi));
  return r;
}
__device__ __forceinline__ bf16x8 cvt8(f32x4 x, f32x4 y) {
  uint4v u;
  u[0] = cvt_pk(x[0], x[1]); u[1] = cvt_pk(x[2], x[3]);
  u[2] = cvt_pk(y[0], y[1]); u[3] = cvt_pk(y[2], y[3]);
  return __builtin_bit_cast(bf16x8, u);
}
__device__ __forceinline__ bf16x8 as_bf(short8 s) {
  return __builtin_bit_cast(bf16x8, s);
}

#define SB __builtin_amdgcn_sched_barrier(0)

#define GLDS16(gsrc, ldst)                                                     \
  __builtin_amdgcn_global_load_lds(                                            \
      (const __attribute__((address_space(1))) unsigned int*)(gsrc),           \
      (__attribute__((address_space(3))) unsigned int*)(ldst), 16, 0, 0)

// ---------------- pre-pass: pack weights to fragment layout -----------------
// chunk(kt) elem bits: wv[12:11] ct[10:9] seg[8:7] l16[6:3] j[2:0]
// holds W[kt*32 + seg*8 + j][wv*64 + ct*16 + l16]
__global__ void prep_pack(const float* __restrict__ W0, const float* __restrict__ W1,
                          const float* __restrict__ W2, const float* __restrict__ W3,
                          const float* __restrict__ W4, const float* __restrict__ Wr,
                          const float* __restrict__ app, const float* __restrict__ b4,
                          unsigned short* __restrict__ pack, float* __restrict__ b4p,
                          float* __restrict__ wrT)
{
  int gid = blockIdx.x * 256 + threadIdx.x;
  if (gid < PTOT) {
    const float* W; int Kreal, base, krow = 0;
    if      (gid < P1B)  { W = W0; Kreal = 63;  base = P0B; }
    else if (gid < P2B)  { W = W1; Kreal = 256; base = P1B; }
    else if (gid < P3B)  { W = W2; Kreal = 512; base = P2B; }
    else if (gid < P4AB) { W = W3; Kreal = 512; base = P3B; }
    else if (gid < P4BB) { W = W4; Kreal = 256; base = P4AB; }
    else                 { W = W4; Kreal = 27;  base = P4BB; krow = 256; }
    int local = gid - base;
    int j   = local & 7;
    int l16 = (local >> 3) & 15;
    int seg = (local >> 7) & 3;
    int ct  = (local >> 9) & 3;
    int wv  = (local >> 11) & 3;
    int kt  = local >> 13;
    int o = wv * 64 + ct * 16 + l16;
    int k = kt * 32 + seg * 8 + j;
    float v = (k < Kreal) ? W[(long)(k + krow) * 256 + o] : 0.f;
    pack[gid] = f2bf(v);
  } else if (gid < PTOT + 256) {
    int o = gid - PTOT;
    float a = b4[o];
    for (int i = 0; i < 48; ++i) a += app[i] * W4[(long)(283 + i) * 256 + o];
    b4p[o] = a;
  } else if (gid < PTOT + 256 + 768) {
    int idx = gid - (PTOT + 256);
    int c = idx >> 8, ch = idx & 255;
    wrT[c * 256 + ch] = Wr[ch * 3 + c];
  }
}

// ---------------- main fused kernel ----------------------------------------
__global__ __launch_bounds__(256, 2)
void nerf_fused(const float* __restrict__ pos, const float* __restrict__ dirs,
                const float* __restrict__ gemo, const float* __restrict__ color,
                const float* __restrict__ mask,
                const unsigned short* __restrict__ wp,
                const float* __restrict__ b0, const float* __restrict__ b1,
                const float* __restrict__ b2, const float* __restrict__ bsv,
                const float* __restrict__ b3, const float* __restrict__ b4p,
                const float* __restrict__ brv,
                const float* __restrict__ Wsf, const float* __restrict__ wrT,
                float* __restrict__ osig, float* __restrict__ orgb)
{
  extern __shared__ unsigned short smem[];
  unsigned short* act  = smem;                       // [64][RS] bf16
  unsigned short* ring = smem + ACT_ELEMS;           // 2 slots x 8KB raw f32
  float* scr = (float*)(smem + ACT_ELEMS + 2 * 4096);  // 3 KB head scratch

  const int tid  = (int)threadIdx.x;
  const int w    = tid >> 6;
  const int lane = tid & 63;
  const int l16  = lane & 15;
  const int seg  = lane >> 4;
  const int chb  = w * 64;              // 4 disjoint 64-ch slices
  const long R0  = (long)blockIdx.x * MT;
  const int rot  = (int)(blockIdx.x & 7);

  f32x4 acc[4][4];

  // stage one 8KB B-chunk (64 rows x 32 f32 cols) cooperatively: 2 glds/thr.
  // unit u holds (row=u>>3, part=(u&7)^(row&7)) -> swizzled b128 reads.
  auto stageB = [&](const float* __restrict__ P, int slot, int c) {
#pragma unroll
    for (int m = 0; m < 2; ++m) {
      int u = m * 256 + w * 64 + lane;
      int row = u >> 3;
      int part = (u & 7) ^ (row & 7);
      const float* src = P + (R0 + row) * 256 + c * 32 + part * 4;
      unsigned short* dst = ring + slot * 4096 + (m * 256 + w * 64) * 8;
      GLDS16(src, dst);
    }
  };
  auto ldB_ring = [&](int slot, int rt, int p) -> f32x4 {
    int row = rt * 16 + l16;
    return *(const f32x4*)(ring + slot * 4096 + (row * 8 + (p ^ (row & 7))) * 8);
  };
  auto ldAd = [&](int baseElems, int kt, int ct) -> bf16x8 {
    return *(const bf16x8*)(wp + baseElems + kt * 8192 + w * 2048 +
                            ((ct * 4 + seg) * 16 + l16) * 8);
  };
  auto ldB_act = [&](int rt, int kt) -> bf16x8 {
    int row = rt * 16 + l16;
    return *(const bf16x8*)(act + row * RS + kt * 32 + seg * 8);
  };
  auto ldB_gen = [&](const float* __restrict__ p, int stride, int Kreal,
                     int rt, int ktl) -> bf16x8 {
    long row = R0 + rt * 16 + l16;
    const float* q = p + row * stride;
    int k0 = ktl * 32 + seg * 8;
    short8 s;
#pragma unroll
    for (int j = 0; j < 8; ++j) {
      float v = (k0 + j < Kreal) ? __builtin_nontemporal_load(q + k0 + j) : 0.0f;
      s[j] = (short)f2bf(v);
    }
    return as_bf(s);
  };
  auto initAcc = [&](const float* __restrict__ b) {
#pragma unroll
    for (int ct = 0; ct < 4; ++ct) {
      float4 bv = *(const float4*)(b + chb + ct * 16 + seg * 4);
      f32x4 t; t[0] = bv.x; t[1] = bv.y; t[2] = bv.z; t[3] = bv.w;
#pragma unroll
      for (int rt = 0; rt < 4; ++rt) acc[ct][rt] = t;
    }
  };
  auto storeAct = [&]() {
#pragma unroll
    for (int ct = 0; ct < 4; ++ct)
#pragma unroll
      for (int rt = 0; rt < 4; ++rt) {
        int row = rt * 16 + l16;
        int ch  = chb + ct * 16 + seg * 4;
        f32x4 v = acc[ct][rt];
        uint2 u;
        u.x = cvt_pk(fmaxf(v[0], 0.f), fmaxf(v[1], 0.f));
        u.y = cvt_pk(fmaxf(v[2], 0.f), fmaxf(v[3], 0.f));
        *(uint2*)(act + row * RS + ch) = u;
      }
  };

#define MFMA16(AFRAG, BFRAGS)                                                  \
  _Pragma("unroll") for (int ct = 0; ct < 4; ++ct) {                           \
    _Pragma("unroll") for (int rt = 0; rt < 4; ++rt)                           \
      acc[ct][rt] = __builtin_amdgcn_mfma_f32_16x16x32_bf16(                   \
          AFRAG[ct], BFRAGS[rt], acc[ct][rt], 0, 0, 0);                        \
  }

// 8 K-steps, B from act LDS, A direct L2 (compiler-scheduled).
#define LHALF(ABASE)                                                           \
  _Pragma("unroll") for (int i = 0; i < 8; ++i) {                              \
    int kt = (i + rot) & 7;                                                    \
    bf16x8 Bf_[4];                                                             \
    _Pragma("unroll") for (int rt = 0; rt < 4; ++rt) Bf_[rt] = ldB_act(rt, kt); \
    bf16x8 Af_[4];                                                             \
    _Pragma("unroll") for (int ct = 0; ct < 4; ++ct) Af_[ct] = ldAd(ABASE, kt, ct); \
    MFMA16(Af_, Bf_);                                                          \
  }

// One stream step, 2-slot ring, AfG depth-2:
// [FENCE(NF)][bar][stage c(i+1)->slot (i+1)&1; AfG[(i+1)&1]][B-read][MFMA]
// Stage-after-barrier is race-free: the barrier certifies every wave's reads
// of that slot's previous chunk (step i-1) completed (MFMA lgkm deps).
// Ledger: chunk i's glds (issued step i-1) are followed only by AfG(i+1)
// (4 ops) -> FENCE(4); c0 is retired by LHALF's own compiler waits (in-order
// retirement); tail FENCE(0).
#define GREG(i, NF)                                                            \
  {                                                                            \
    asm volatile("s_waitcnt vmcnt(" #NF ")" ::: "memory"); SB;                 \
    __builtin_amdgcn_s_barrier(); SB;                                          \
    if ((i) + 1 < 8) {                                                         \
      stageB(GP, ((i) + 1) & 1, ((i) + 1 + rot) & 7);                          \
      _Pragma("unroll") for (int ct = 0; ct < 4; ++ct)                         \
        AfG[((i) + 1) & 1][ct] = ldAd(GABASE, 8 + (((i) + 1 + rot) & 7), ct);  \
    }                                                                          \
    SB;                                                                        \
    bf16x8 Bf_[4];                                                             \
    _Pragma("unroll") for (int rt = 0; rt < 4; ++rt) {                         \
      f32x4 lo = ldB_ring((i) & 1, rt, 2 * seg);                               \
      f32x4 hi = ldB_ring((i) & 1, rt, 2 * seg + 1);                           \
      Bf_[rt] = cvt8(lo, hi);                                                  \
    }                                                                          \
    MFMA16(AfG[(i) & 1], Bf_);                                                 \
  }

#define GHALF(ABASE, P)                                                        \
  {                                                                            \
    const int GABASE = (ABASE); const float* __restrict__ GP = (P);            \
    bf16x8 AfG[2][4];                                                          \
    SB;                                                                        \
    _Pragma("unroll") for (int ct = 0; ct < 4; ++ct)                           \
      AfG[0][ct] = ldAd(GABASE, 8 + (rot & 7), ct);                            \
    SB;                                                                        \
    GREG(0, 4) GREG(1, 4) GREG(2, 4) GREG(3, 4)                                \
    GREG(4, 4) GREG(5, 4) GREG(6, 4) GREG(7, 0)                                \
  }

  // ---- L0: d0 = relu(pos @ W0 + b0) -> act
  initAcc(b0);
#pragma unroll
  for (int kt = 0; kt < 2; ++kt) {
    bf16x8 Bf_[4];
#pragma unroll
    for (int rt = 0; rt < 4; ++rt) Bf_[rt] = ldB_gen(pos, 63, 63, rt, kt);
    bf16x8 Af_[4];
#pragma unroll
    for (int ct = 0; ct < 4; ++ct) Af_[ct] = ldAd(P0B, kt, ct);
    MFMA16(Af_, Bf_);
  }
  storeAct();
  __syncthreads();

  // ---- L1: d1 = relu(d0 @ W1 + b1); act: d0 -> d1
  initAcc(b1);
  LHALF(P1B);
  __syncthreads();
  storeAct();
  __syncthreads();

  // ---- L2: d2 = [d1|gemo] @ W2 + b2 (stays in acc)
  SB; stageB(gemo, 0, rot & 7); SB;   // c0 flies across LHALF's 8 steps
  initAcc(b2);
  LHALF(P2B);
  GHALF(P2B, gemo);

  // ---- sigma head (in-register): softplus(relu(d2) @ Ws + bs) * mask
  {
    float p[4];
#pragma unroll
    for (int rt = 0; rt < 4; ++rt) {
      float s = 0.f;
#pragma unroll
      for (int ct = 0; ct < 4; ++ct) {
        float4 w4 = *(const float4*)(Wsf + chb + ct * 16 + seg * 4);
        f32x4 a = acc[ct][rt];
        s += fmaxf(a[0], 0.f) * w4.x + fmaxf(a[1], 0.f) * w4.y +
             fmaxf(a[2], 0.f) * w4.z + fmaxf(a[3], 0.f) * w4.w;
      }
      s += __shfl_xor(s, 16);
      s += __shfl_xor(s, 32);
      p[rt] = s;
    }
    if (seg == 0) {
#pragma unroll
      for (int rt = 0; rt < 4; ++rt) scr[w * 64 + rt * 16 + l16] = p[rt];
    }
  }
  __syncthreads();
  if (tid < 64) {
    float s = scr[tid] + scr[64 + tid] + scr[128 + tid] + scr[192 + tid] + bsv[0];
    float sp = fmaxf(s, 0.f) + log1pf(expf(-fabsf(s)));
    float m = __builtin_nontemporal_load(mask + R0 + tid);
    __builtin_nontemporal_store(sp * m, osig + R0 + tid);
  }

  // ---- L3: d3 = relu([d1|color] @ W3 + b3); act: d1 -> d3
  SB; stageB(color, 0, rot & 7); SB;  // c0 flies across LHALF's 8 steps
  initAcc(b3);
  LHALF(P3B);
  GHALF(P3B, color);
  __syncthreads();
  storeAct();
  __syncthreads();

  // ---- L4: d4 = [d3|dir|app] @ W4 + b4' (stays in acc)
  initAcc(b4p);
  LHALF(P4AB);
  {  // dir step (K=32, direct A)
    bf16x8 Bf_[4];
#pragma unroll
    for (int rt = 0; rt < 4; ++rt) Bf_[rt] = ldB_gen(dirs, 27, 27, rt, 0);
    bf16x8 Af_[4];
#pragma unroll
    for (int ct = 0; ct < 4; ++ct) Af_[ct] = ldAd(P4BB, 0, ct);
    MFMA16(Af_, Bf_);
  }

  // ---- rgb head (in-register): sigmoid(relu(d4) @ Wr + br)
  {
#pragma unroll
    for (int ct = 0; ct < 4; ++ct)
#pragma unroll
      for (int rt = 0; rt < 4; ++rt) {
        f32x4 a = acc[ct][rt];
        a[0] = fmaxf(a[0], 0.f); a[1] = fmaxf(a[1], 0.f);
        a[2] = fmaxf(a[2], 0.f); a[3] = fmaxf(a[3], 0.f);
        acc[ct][rt] = a;
      }
#pragma unroll
    for (int c = 0; c < 3; ++c) {
      float p[4];
#pragma unroll
      for (int rt = 0; rt < 4; ++rt) {
        float s = 0.f;
#pragma unroll
        for (int ct = 0; ct < 4; ++ct) {
          float4 w4 = *(const float4*)(wrT + c * 256 + chb + ct * 16 + seg * 4);
          f32x4 a = acc[ct][rt];
          s += a[0] * w4.x + a[1] * w4.y + a[2] * w4.z + a[3] * w4.w;
        }
        s += __shfl_xor(s, 16);
        s += __shfl_xor(s, 32);
        p[rt] = s;
      }
      if (seg == 0) {
#pragma unroll
        for (int rt = 0; rt < 4; ++rt)
          scr[c * 256 + w * 64 + rt * 16 + l16] = p[rt];
      }
    }
  }
  __syncthreads();
  if (tid < 64) {
#pragma unroll
    for (int c = 0; c < 3; ++c) {
      float s = scr[c * 256 + tid] + scr[c * 256 + 64 + tid] +
                scr[c * 256 + 128 + tid] + scr[c * 256 + 192 + tid] + brv[c];
      float r = 1.f / (1.f + expf(-s));
      __builtin_nontemporal_store(r, orgb + (R0 + tid) * 3 + c);
    }
  }
#undef MFMA16
#undef LHALF
#undef GREG
#undef GHALF
}

extern "C" void kernel_launch(void* const* d_in, const int* in_sizes, int n_in,
                              void* d_out, int out_size, void* d_ws, size_t ws_size,
                              hipStream_t stream) {
  const float* pos   = (const float*)d_in[0];
  const float* dirs  = (const float*)d_in[1];
  const float* app   = (const float*)d_in[2];
  const float* gemo  = (const float*)d_in[3];
  const float* color = (const float*)d_in[4];
  const float* mask  = (const float*)d_in[5];
  // d_in[6] = num_inters (fixed 32, shapes are static)
  const float* W0 = (const float*)d_in[7];   const float* b0 = (const float*)d_in[8];
  const float* W1 = (const float*)d_in[9];   const float* b1 = (const float*)d_in[10];
  const float* W2 = (const float*)d_in[11];  const float* b2 = (const float*)d_in[12];
  const float* Ws = (const float*)d_in[13];  const float* bs = (const float*)d_in[14];
  const float* W3 = (const float*)d_in[15];  const float* b3 = (const float*)d_in[16];
  const float* W4 = (const float*)d_in[17];  const float* b4 = (const float*)d_in[18];
  const float* Wr = (const float*)d_in[19];  const float* br = (const float*)d_in[20];

  unsigned short* pack = (unsigned short*)d_ws;
  float* b4p = (float*)((char*)d_ws + (size_t)PTOT * 2);
  float* wrT = b4p + 256;

  float* osig = (float*)d_out;
  float* orgb = osig + NROWS;

  prep_pack<<<dim3((PTOT + 256 + 768 + 255) / 256), dim3(256), 0, stream>>>(
      W0, W1, W2, W3, W4, Wr, app, b4, pack, b4p, wrT);

  hipFuncSetAttribute((const void*)nerf_fused,
                      hipFuncAttributeMaxDynamicSharedMemorySize, SMEM_BYTES);

  nerf_fused<<<dim3(NROWS / MT), dim3(256), SMEM_BYTES, stream>>>(
      pos, dirs, gemo, color, mask, pack,
      b0, b1, b2, bs, b3, b4p, br, Ws, wrT, osig, orgb);
}

// Round 12
// 439.828 us; speedup vs baseline: 1.2111x; 1.0740x over previous
//
#include <hip/hip_runtime.h>

// Fused NeRF-MLP. Round 12: push into the 3-waves/SIMD occupancy tier.
// Occupancy tier = arch VGPR + AGPR (acc): 164 unified -> 2 waves/SIMD in
// R8-R11. Shave arch regs via manual address CSE (uniform SGPR chunk ptrs +
// literal immediates everywhere; rot dropped from LHALF to make kt literal)
// + __launch_bounds__(256,3). LDS 52.7KB (R11) already fits 3 blocks/CU.
// Structure otherwise frozen at R11 (glds B-ring 2-slot, AfG[2], heads).
// 4096 blocks x 256 thr (4 waves), 64 rows/block, wave = 64ch x 64rows.

typedef __bf16 bf16x8 __attribute__((ext_vector_type(8)));
typedef float  f32x4  __attribute__((ext_vector_type(4)));
typedef short  short8 __attribute__((ext_vector_type(8)));
typedef unsigned int uint4v __attribute__((ext_vector_type(4)));

#define NROWS (8192 * 32)
#define MT 64
#define RS 260   // act row stride (520B; 0 measured conflicts since R7)

// packed-weight layout (bf16 elems): kt chunks of 8192 elems, lane-linear.
#define P0B   0        // W0^T  K=64 (pad 63)  : 2 kt
#define P1B   16384    // W1    K=256          : 8 kt
#define P2B   81920    // W2    K=512          : 16 kt
#define P3B   212992   // W3    K=512          : 16 kt
#define P4AB  344064   // W4[:256]   K=256     : 8 kt
#define P4BB  409600   // W4[256:283] K=32(27) : 1 kt
#define PTOT  417792

#define ACT_ELEMS (MT * RS)                     // 16640 ushorts = 33280 B
// act 33280 + ring 2*8192 + scr 3072 = 52736 B -> 3 blocks/CU (158208<=163840)
#define SMEM_BYTES (ACT_ELEMS * 2 + 2 * 8192 + 3072)

__device__ __forceinline__ unsigned short f2bf(float f) {
  unsigned u = __builtin_bit_cast(unsigned, f);
  u += 0x7fffu + ((u >> 16) & 1u);   // RNE
  return (unsigned short)(u >> 16);
}
__device__ __forceinline__ unsigned cvt_pk(float lo, float hi) {
  unsigned r;
  asm("v_cvt_pk_bf16_f32 %0, %1, %2" : "=v"(r) : "v"(lo), "v"(hi));
  return r;
}
__device__ __forceinline__ bf16x8 cvt8(f32x4 x, f32x4 y) {
  uint4v u;
  u[0] = cvt_pk(x[0], x[1]); u[1] = cvt_pk(x[2], x[3]);
  u[2] = cvt_pk(y[0], y[1]); u[3] = cvt_pk(y[2], y[3]);
  return __builtin_bit_cast(bf16x8, u);
}
__device__ __forceinline__ bf16x8 as_bf(short8 s) {
  return __builtin_bit_cast(bf16x8, s);
}

#define SB __builtin_amdgcn_sched_barrier(0)

#define GLDS16(gsrc, ldst)                                                     \
  __builtin_amdgcn_global_load_lds(                                            \
      (const __attribute__((address_space(1))) unsigned int*)(gsrc),           \
      (__attribute__((address_space(3))) unsigned int*)(ldst), 16, 0, 0)

// ---------------- pre-pass: pack weights to fragment layout -----------------
// chunk(kt) elem bits: wv[12:11] ct[10:9] seg[8:7] l16[6:3] j[2:0]
// holds W[kt*32 + seg*8 + j][wv*64 + ct*16 + l16]
__global__ void prep_pack(const float* __restrict__ W0, const float* __restrict__ W1,
                          const float* __restrict__ W2, const float* __restrict__ W3,
                          const float* __restrict__ W4, const float* __restrict__ Wr,
                          const float* __restrict__ app, const float* __restrict__ b4,
                          unsigned short* __restrict__ pack, float* __restrict__ b4p,
                          float* __restrict__ wrT)
{
  int gid = blockIdx.x * 256 + threadIdx.x;
  if (gid < PTOT) {
    const float* W; int Kreal, base, krow = 0;
    if      (gid < P1B)  { W = W0; Kreal = 63;  base = P0B; }
    else if (gid < P2B)  { W = W1; Kreal = 256; base = P1B; }
    else if (gid < P3B)  { W = W2; Kreal = 512; base = P2B; }
    else if (gid < P4AB) { W = W3; Kreal = 512; base = P3B; }
    else if (gid < P4BB) { W = W4; Kreal = 256; base = P4AB; }
    else                 { W = W4; Kreal = 27;  base = P4BB; krow = 256; }
    int local = gid - base;
    int j   = local & 7;
    int l16 = (local >> 3) & 15;
    int seg = (local >> 7) & 3;
    int ct  = (local >> 9) & 3;
    int wv  = (local >> 11) & 3;
    int kt  = local >> 13;
    int o = wv * 64 + ct * 16 + l16;
    int k = kt * 32 + seg * 8 + j;
    float v = (k < Kreal) ? W[(long)(k + krow) * 256 + o] : 0.f;
    pack[gid] = f2bf(v);
  } else if (gid < PTOT + 256) {
    int o = gid - PTOT;
    float a = b4[o];
    for (int i = 0; i < 48; ++i) a += app[i] * W4[(long)(283 + i) * 256 + o];
    b4p[o] = a;
  } else if (gid < PTOT + 256 + 768) {
    int idx = gid - (PTOT + 256);
    int c = idx >> 8, ch = idx & 255;
    wrT[c * 256 + ch] = Wr[ch * 3 + c];
  }
}

// ---------------- main fused kernel ----------------------------------------
__global__ __launch_bounds__(256, 3)
void nerf_fused(const float* __restrict__ pos, const float* __restrict__ dirs,
                const float* __restrict__ gemo, const float* __restrict__ color,
                const float* __restrict__ mask,
                const unsigned short* __restrict__ wp,
                const float* __restrict__ b0, const float* __restrict__ b1,
                const float* __restrict__ b2, const float* __restrict__ bsv,
                const float* __restrict__ b3, const float* __restrict__ b4p,
                const float* __restrict__ brv,
                const float* __restrict__ Wsf, const float* __restrict__ wrT,
                float* __restrict__ osig, float* __restrict__ orgb)
{
  extern __shared__ unsigned short smem[];
  unsigned short* act  = smem;                       // [64][RS] bf16
  unsigned short* ring = smem + ACT_ELEMS;           // 2 slots x 8KB raw f32
  float* scr = (float*)(smem + ACT_ELEMS + 2 * 4096);  // 3 KB head scratch

  const int tid  = (int)threadIdx.x;
  const int w    = tid >> 6;
  const int lane = tid & 63;
  const int l16  = lane & 15;
  const int seg  = lane >> 4;
  const int chb  = w * 64;              // 4 disjoint 64-ch slices
  const long R0  = (long)blockIdx.x * MT;
  const int rot  = (int)(blockIdx.x & 7);

  // ---- precomputed per-lane bases (address CSE; ct/rt/kt/slot as literals)
  const int wlane = w * 2048 + (seg * 16 + l16) * 8;         // weight elem off
  unsigned short* const actl = act + l16 * RS + seg * 8;     // act read base
  unsigned short* const actw = act + l16 * RS + chb + seg * 4; // act write base
  const int swz0 = (2 * seg) ^ (l16 & 7);
  unsigned short* const ringl0 = ring + l16 * 64 + swz0 * 8;       // ring bases
  unsigned short* const ringl1 = ring + l16 * 64 + (swz0 ^ 1) * 8;
  const int row0 = tid >> 3,          part0 = (tid & 7) ^ (row0 & 7);
  const int row1 = (tid + 256) >> 3,  part1 = (tid & 7) ^ (row1 & 7);
  const int soff0 = row0 * 256 + part0 * 4;   // stage src f32-elem offsets
  const int soff1 = row1 * 256 + part1 * 4;
  unsigned short* const sdst0 = ring + tid * 8;
  unsigned short* const sdst1 = ring + (tid + 256) * 8;
  const float* const gemoB  = gemo  + R0 * 256;
  const float* const colorB = color + R0 * 256;

  f32x4 acc[4][4];

  auto ldA2 = [&](const unsigned short* __restrict__ chunk, int ct) -> bf16x8 {
    return *(const bf16x8*)(chunk + wlane + ct * 512);       // imm ct*1024B
  };
  auto stageB = [&](const float* __restrict__ Pb, int slot, int c) {
    GLDS16(Pb + c * 32 + soff0, sdst0 + slot * 4096);
    GLDS16(Pb + c * 32 + soff1, sdst1 + slot * 4096);
  };
  auto ldR = [&](unsigned short* base, int slot, int rt) -> f32x4 {
    return *(const f32x4*)(base + slot * 4096 + rt * 1024);  // imm slot*8K+rt*2K
  };
  auto ldB_gen = [&](const float* __restrict__ p, int stride, int Kreal,
                     int rt, int ktl) -> bf16x8 {
    long row = R0 + rt * 16 + l16;
    const float* q = p + row * stride;
    int k0 = ktl * 32 + seg * 8;
    short8 s;
#pragma unroll
    for (int j = 0; j < 8; ++j) {
      float v = (k0 + j < Kreal) ? __builtin_nontemporal_load(q + k0 + j) : 0.0f;
      s[j] = (short)f2bf(v);
    }
    return as_bf(s);
  };
  auto initAcc = [&](const float* __restrict__ b) {
#pragma unroll
    for (int ct = 0; ct < 4; ++ct) {
      float4 bv = *(const float4*)(b + chb + ct * 16 + seg * 4);
      f32x4 t; t[0] = bv.x; t[1] = bv.y; t[2] = bv.z; t[3] = bv.w;
#pragma unroll
      for (int rt = 0; rt < 4; ++rt) acc[ct][rt] = t;
    }
  };
  auto storeAct = [&]() {
#pragma unroll
    for (int ct = 0; ct < 4; ++ct)
#pragma unroll
      for (int rt = 0; rt < 4; ++rt) {
        f32x4 v = acc[ct][rt];
        uint2 u;
        u.x = cvt_pk(fmaxf(v[0], 0.f), fmaxf(v[1], 0.f));
        u.y = cvt_pk(fmaxf(v[2], 0.f), fmaxf(v[3], 0.f));
        *(uint2*)(actw + rt * (16 * RS) + ct * 16) = u;      // imm rt*8320+ct*32
      }
  };

#define MFMA16(AFRAG, BFRAGS)                                                  \
  _Pragma("unroll") for (int ct = 0; ct < 4; ++ct) {                           \
    _Pragma("unroll") for (int rt = 0; rt < 4; ++rt)                           \
      acc[ct][rt] = __builtin_amdgcn_mfma_f32_16x16x32_bf16(                   \
          AFRAG[ct], BFRAGS[rt], acc[ct][rt], 0, 0, 0);                        \
  }

// 8 K-steps, B from act LDS (static imm addressing), A via uniform chunk ptr.
#define LHALF(WBASE)                                                           \
  _Pragma("unroll") for (int i = 0; i < 8; ++i) {                              \
    const unsigned short* ch_ = (WBASE) + i * 8192;                            \
    bf16x8 Bf_[4];                                                             \
    _Pragma("unroll") for (int rt = 0; rt < 4; ++rt)                           \
      Bf_[rt] = *(const bf16x8*)(actl + rt * (16 * RS) + i * 32);              \
    bf16x8 Af_[4];                                                             \
    _Pragma("unroll") for (int ct = 0; ct < 4; ++ct) Af_[ct] = ldA2(ch_, ct);  \
    MFMA16(Af_, Bf_);                                                          \
  }

// One stream step, 2-slot ring, AfG depth-2 (semantics = R11's GREG):
// [FENCE(4)][bar][stage c(i+1) + AfG(i+1)][ring-read + cvt][MFMA(i)]
// Ledger: at fence, outstanding = stage c(i) (2, oldest) + AfG(i) (4);
// FENCE(4) drains exactly stage c(i) -> slot i&1 ready. AfG(i) retired by
// the MFMA's compiler-auto wait. Stage-after-barrier is race-free (barrier
// certifies all reads of that slot's previous chunk were consumed by MFMA).
#define GREG(i)                                                                \
  {                                                                            \
    asm volatile("s_waitcnt vmcnt(4)" ::: "memory"); SB;                       \
    __builtin_amdgcn_s_barrier(); SB;                                          \
    if ((i) + 1 < 8) {                                                         \
      int cn = ((i) + 1 + rot) & 7;                                            \
      stageB(GP, ((i) + 1) & 1, cn);                                           \
      const unsigned short* chn_ = GW + (8 + cn) * 8192;                       \
      AfG[((i) + 1) & 1][0] = ldA2(chn_, 0);                                   \
      AfG[((i) + 1) & 1][1] = ldA2(chn_, 1);                                   \
      AfG[((i) + 1) & 1][2] = ldA2(chn_, 2);                                   \
      AfG[((i) + 1) & 1][3] = ldA2(chn_, 3);                                   \
    }                                                                          \
    SB;                                                                        \
    bf16x8 Bf_[4];                                                             \
    _Pragma("unroll") for (int rt = 0; rt < 4; ++rt) {                         \
      f32x4 lo = ldR(ringl0, (i) & 1, rt);                                     \
      f32x4 hi = ldR(ringl1, (i) & 1, rt);                                     \
      Bf_[rt] = cvt8(lo, hi);                                                  \
    }                                                                          \
    MFMA16(AfG[(i) & 1], Bf_);                                                 \
  }

#define GHALF(WBASE, PB)                                                       \
  {                                                                            \
    const unsigned short* GW = (WBASE);                                        \
    const float* __restrict__ GP = (PB);                                       \
    bf16x8 AfG[2][4];                                                          \
    SB;                                                                        \
    { const unsigned short* ch_ = GW + (8 + (rot & 7)) * 8192;                 \
      AfG[0][0] = ldA2(ch_, 0); AfG[0][1] = ldA2(ch_, 1);                      \
      AfG[0][2] = ldA2(ch_, 2); AfG[0][3] = ldA2(ch_, 3); }                    \
    SB;                                                                        \
    GREG(0) GREG(1) GREG(2) GREG(3)                                            \
    GREG(4) GREG(5) GREG(6) GREG(7)                                            \
  }

  // ---- L0: d0 = relu(pos @ W0 + b0) -> act
  initAcc(b0);
#pragma unroll
  for (int kt = 0; kt < 2; ++kt) {
    const unsigned short* ch0 = wp + P0B + kt * 8192;
    bf16x8 Bf_[4];
#pragma unroll
    for (int rt = 0; rt < 4; ++rt) Bf_[rt] = ldB_gen(pos, 63, 63, rt, kt);
    bf16x8 Af_[4];
#pragma unroll
    for (int ct = 0; ct < 4; ++ct) Af_[ct] = ldA2(ch0, ct);
    MFMA16(Af_, Bf_);
  }
  storeAct();
  __syncthreads();

  // ---- L1: d1 = relu(d0 @ W1 + b1); act: d0 -> d1
  initAcc(b1);
  LHALF(wp + P1B);
  __syncthreads();
  storeAct();
  __syncthreads();

  // ---- L2: d2 = [d1|gemo] @ W2 + b2 (stays in acc)
  SB; stageB(gemoB, 0, rot & 7); SB;   // c0 flies across LHALF's 8 steps
  initAcc(b2);
  LHALF(wp + P2B);
  GHALF(wp + P2B, gemoB);

  // ---- sigma head (in-register): softplus(relu(d2) @ Ws + bs) * mask
  {
    float p[4];
#pragma unroll
    for (int rt = 0; rt < 4; ++rt) {
      float s = 0.f;
#pragma unroll
      for (int ct = 0; ct < 4; ++ct) {
        float4 w4 = *(const float4*)(Wsf + chb + ct * 16 + seg * 4);
        f32x4 a = acc[ct][rt];
        s += fmaxf(a[0], 0.f) * w4.x + fmaxf(a[1], 0.f) * w4.y +
             fmaxf(a[2], 0.f) * w4.z + fmaxf(a[3], 0.f) * w4.w;
      }
      s += __shfl_xor(s, 16);
      s += __shfl_xor(s, 32);
      p[rt] = s;
    }
    if (seg == 0) {
#pragma unroll
      for (int rt = 0; rt < 4; ++rt) scr[w * 64 + rt * 16 + l16] = p[rt];
    }
  }
  __syncthreads();
  if (tid < 64) {
    float s = scr[tid] + scr[64 + tid] + scr[128 + tid] + scr[192 + tid] + bsv[0];
    float sp = fmaxf(s, 0.f) + log1pf(expf(-fabsf(s)));
    float m = __builtin_nontemporal_load(mask + R0 + tid);
    __builtin_nontemporal_store(sp * m, osig + R0 + tid);
  }

  // ---- L3: d3 = relu([d1|color] @ W3 + b3); act: d1 -> d3
  SB; stageB(colorB, 0, rot & 7); SB;  // c0 flies across LHALF's 8 steps
  initAcc(b3);
  LHALF(wp + P3B);
  GHALF(wp + P3B, colorB);
  __syncthreads();
  storeAct();
  __syncthreads();

  // ---- L4: d4 = [d3|dir|app] @ W4 + b4' (stays in acc)
  initAcc(b4p);
  LHALF(wp + P4AB);
  {  // dir step (K=32, direct A)
    const unsigned short* ch4 = wp + P4BB;
    bf16x8 Bf_[4];
#pragma unroll
    for (int rt = 0; rt < 4; ++rt) Bf_[rt] = ldB_gen(dirs, 27, 27, rt, 0);
    bf16x8 Af_[4];
#pragma unroll
    for (int ct = 0; ct < 4; ++ct) Af_[ct] = ldA2(ch4, ct);
    MFMA16(Af_, Bf_);
  }

  // ---- rgb head (in-register): sigmoid(relu(d4) @ Wr + br)
  {
#pragma unroll
    for (int ct = 0; ct < 4; ++ct)
#pragma unroll
      for (int rt = 0; rt < 4; ++rt) {
        f32x4 a = acc[ct][rt];
        a[0] = fmaxf(a[0], 0.f); a[1] = fmaxf(a[1], 0.f);
        a[2] = fmaxf(a[2], 0.f); a[3] = fmaxf(a[3], 0.f);
        acc[ct][rt] = a;
      }
#pragma unroll
    for (int c = 0; c < 3; ++c) {
      float p[4];
#pragma unroll
      for (int rt = 0; rt < 4; ++rt) {
        float s = 0.f;
#pragma unroll
        for (int ct = 0; ct < 4; ++ct) {
          float4 w4 = *(const float4*)(wrT + c * 256 + chb + ct * 16 + seg * 4);
          f32x4 a = acc[ct][rt];
          s += a[0] * w4.x + a[1] * w4.y + a[2] * w4.z + a[3] * w4.w;
        }
        s += __shfl_xor(s, 16);
        s += __shfl_xor(s, 32);
        p[rt] = s;
      }
      if (seg == 0) {
#pragma unroll
        for (int rt = 0; rt < 4; ++rt)
          scr[c * 256 + w * 64 + rt * 16 + l16] = p[rt];
      }
    }
  }
  __syncthreads();
  if (tid < 64) {
#pragma unroll
    for (int c = 0; c < 3; ++c) {
      float s = scr[c * 256 + tid] + scr[c * 256 + 64 + tid] +
                scr[c * 256 + 128 + tid] + scr[c * 256 + 192 + tid] + brv[c];
      float r = 1.f / (1.f + expf(-s));
      __builtin_nontemporal_store(r, orgb + (R0 + tid) * 3 + c);
    }
  }
#undef MFMA16
#undef LHALF
#undef GREG
#undef GHALF
}

extern "C" void kernel_launch(void* const* d_in, const int* in_sizes, int n_in,
                              void* d_out, int out_size, void* d_ws, size_t ws_size,
                              hipStream_t stream) {
  const float* pos   = (const float*)d_in[0];
  const float* dirs  = (const float*)d_in[1];
  const float* app   = (const float*)d_in[2];
  const float* gemo  = (const float*)d_in[3];
  const float* color = (const float*)d_in[4];
  const float* mask  = (const float*)d_in[5];
  // d_in[6] = num_inters (fixed 32, shapes are static)
  const float* W0 = (const float*)d_in[7];   const float* b0 = (const float*)d_in[8];
  const float* W1 = (const float*)d_in[9];   const float* b1 = (const float*)d_in[10];
  const float* W2 = (const float*)d_in[11];  const float* b2 = (const float*)d_in[12];
  const float* Ws = (const float*)d_in[13];  const float* bs = (const float*)d_in[14];
  const float* W3 = (const float*)d_in[15];  const float* b3 = (const float*)d_in[16];
  const float* W4 = (const float*)d_in[17];  const float* b4 = (const float*)d_in[18];
  const float* Wr = (const float*)d_in[19];  const float* br = (const float*)d_in[20];

  unsigned short* pack = (unsigned short*)d_ws;
  float* b4p = (float*)((char*)d_ws + (size_t)PTOT * 2);
  float* wrT = b4p + 256;

  float* osig = (float*)d_out;
  float* orgb = osig + NROWS;

  prep_pack<<<dim3((PTOT + 256 + 768 + 255) / 256), dim3(256), 0, stream>>>(
      W0, W1, W2, W3, W4, Wr, app, b4, pack, b4p, wrT);

  hipFuncSetAttribute((const void*)nerf_fused,
                      hipFuncAttributeMaxDynamicSharedMemorySize, SMEM_BYTES);

  nerf_fused<<<dim3(NROWS / MT), dim3(256), SMEM_BYTES, stream>>>(
      pos, dirs, gemo, color, mask, pack,
      b0, b1, b2, bs, b3, b4p, br, Ws, wrT, osig, orgb);
}

// Round 13
// 438.709 us; speedup vs baseline: 1.2142x; 1.0025x over previous
//
#include <hip/hip_runtime.h>

// Fused NeRF-MLP. Round 12: push into the 3-waves/SIMD occupancy tier.
// Occupancy tier = arch VGPR + AGPR (acc): 164 unified -> 2 waves/SIMD in
// R8-R11. Shave arch regs via manual address CSE (uniform SGPR chunk ptrs +
// literal immediates everywhere; rot dropped from LHALF to make kt literal)
// + __launch_bounds__(256,3). LDS 52.7KB (R11) already fits 3 blocks/CU.
// Structure otherwise frozen at R11 (glds B-ring 2-slot, AfG[2], heads).
// 4096 blocks x 256 thr (4 waves), 64 rows/block, wave = 64ch x 64rows.

typedef __bf16 bf16x8 __attribute__((ext_vector_type(8)));
typedef float  f32x4  __attribute__((ext_vector_type(4)));
typedef short  short8 __attribute__((ext_vector_type(8)));
typedef unsigned int uint4v __attribute__((ext_vector_type(4)));

#define NROWS (8192 * 32)
#define MT 64
#define RS 260   // act row stride (520B; 0 measured conflicts since R7)

// packed-weight layout (bf16 elems): kt chunks of 8192 elems, lane-linear.
#define P0B   0        // W0^T  K=64 (pad 63)  : 2 kt
#define P1B   16384    // W1    K=256          : 8 kt
#define P2B   81920    // W2    K=512          : 16 kt
#define P3B   212992   // W3    K=512          : 16 kt
#define P4AB  344064   // W4[:256]   K=256     : 8 kt
#define P4BB  409600   // W4[256:283] K=32(27) : 1 kt
#define PTOT  417792

#define ACT_ELEMS (MT * RS)                     // 16640 ushorts = 33280 B
// act 33280 + ring 2*8192 + scr 3072 = 52736 B -> 3 blocks/CU (158208<=163840)
#define SMEM_BYTES (ACT_ELEMS * 2 + 2 * 8192 + 3072)

__device__ __forceinline__ unsigned short f2bf(float f) {
  unsigned u = __builtin_bit_cast(unsigned, f);
  u += 0x7fffu + ((u >> 16) & 1u);   // RNE
  return (unsigned short)(u >> 16);
}
__device__ __forceinline__ unsigned cvt_pk(float lo, float hi) {
  unsigned r;
  asm("v_cvt_pk_bf16_f32 %0, %1, %2" : "=v"(r) : "v"(lo), "v"(hi));
  return r;
}
__device__ __forceinline__ bf16x8 cvt8(f32x4 x, f32x4 y) {
  uint4v u;
  u[0] = cvt_pk(x[0], x[1]); u[1] = cvt_pk(x[2], x[3]);
  u[2] = cvt_pk(y[0], y[1]); u[3] = cvt_pk(y[2], y[3]);
  return __builtin_bit_cast(bf16x8, u);
}
__device__ __forceinline__ bf16x8 as_bf(short8 s) {
  return __builtin_bit_cast(bf16x8, s);
}

#define SB __builtin_amdgcn_sched_barrier(0)

#define GLDS16(gsrc, ldst)                                                     \
  __builtin_amdgcn_global_load_lds(                                            \
      (const __attribute__((address_space(1))) unsigned int*)(gsrc),           \
      (__attribute__((address_space(3))) unsigned int*)(ldst), 16, 0, 0)

// ---------------- pre-pass: pack weights to fragment layout -----------------
// chunk(kt) elem bits: wv[12:11] ct[10:9] seg[8:7] l16[6:3] j[2:0]
// holds W[kt*32 + seg*8 + j][wv*64 + ct*16 + l16]
__global__ void prep_pack(const float* __restrict__ W0, const float* __restrict__ W1,
                          const float* __restrict__ W2, const float* __restrict__ W3,
                          const float* __restrict__ W4, const float* __restrict__ Wr,
                          const float* __restrict__ app, const float* __restrict__ b4,
                          unsigned short* __restrict__ pack, float* __restrict__ b4p,
                          float* __restrict__ wrT)
{
  int gid = blockIdx.x * 256 + threadIdx.x;
  if (gid < PTOT) {
    const float* W; int Kreal, base, krow = 0;
    if      (gid < P1B)  { W = W0; Kreal = 63;  base = P0B; }
    else if (gid < P2B)  { W = W1; Kreal = 256; base = P1B; }
    else if (gid < P3B)  { W = W2; Kreal = 512; base = P2B; }
    else if (gid < P4AB) { W = W3; Kreal = 512; base = P3B; }
    else if (gid < P4BB) { W = W4; Kreal = 256; base = P4AB; }
    else                 { W = W4; Kreal = 27;  base = P4BB; krow = 256; }
    int local = gid - base;
    int j   = local & 7;
    int l16 = (local >> 3) & 15;
    int seg = (local >> 7) & 3;
    int ct  = (local >> 9) & 3;
    int wv  = (local >> 11) & 3;
    int kt  = local >> 13;
    int o = wv * 64 + ct * 16 + l16;
    int k = kt * 32 + seg * 8 + j;
    float v = (k < Kreal) ? W[(long)(k + krow) * 256 + o] : 0.f;
    pack[gid] = f2bf(v);
  } else if (gid < PTOT + 256) {
    int o = gid - PTOT;
    float a = b4[o];
    for (int i = 0; i < 48; ++i) a += app[i] * W4[(long)(283 + i) * 256 + o];
    b4p[o] = a;
  } else if (gid < PTOT + 256 + 768) {
    int idx = gid - (PTOT + 256);
    int c = idx >> 8, ch = idx & 255;
    wrT[c * 256 + ch] = Wr[ch * 3 + c];
  }
}

// ---------------- main fused kernel ----------------------------------------
__global__ __launch_bounds__(256, 3)
void nerf_fused(const float* __restrict__ pos, const float* __restrict__ dirs,
                const float* __restrict__ gemo, const float* __restrict__ color,
                const float* __restrict__ mask,
                const unsigned short* __restrict__ wp,
                const float* __restrict__ b0, const float* __restrict__ b1,
                const float* __restrict__ b2, const float* __restrict__ bsv,
                const float* __restrict__ b3, const float* __restrict__ b4p,
                const float* __restrict__ brv,
                const float* __restrict__ Wsf, const float* __restrict__ wrT,
                float* __restrict__ osig, float* __restrict__ orgb)
{
  extern __shared__ unsigned short smem[];
  unsigned short* act  = smem;                       // [64][RS] bf16
  unsigned short* ring = smem + ACT_ELEMS;           // 2 slots x 8KB raw f32
  float* scr = (float*)(smem + ACT_ELEMS + 2 * 4096);  // 3 KB head scratch

  const int tid  = (int)threadIdx.x;
  const int w    = tid >> 6;
  const int lane = tid & 63;
  const int l16  = lane & 15;
  const int seg  = lane >> 4;
  const int chb  = w * 64;              // 4 disjoint 64-ch slices
  const long R0  = (long)blockIdx.x * MT;
  const int rot  = (int)(blockIdx.x & 7);

  // ---- precomputed per-lane bases (address CSE; ct/rt/kt/slot as literals)
  const int wlane = w * 2048 + (seg * 16 + l16) * 8;         // weight elem off
  unsigned short* const actl = act + l16 * RS + seg * 8;     // act read base
  unsigned short* const actw = act + l16 * RS + chb + seg * 4; // act write base
  const int swz0 = (2 * seg) ^ (l16 & 7);
  unsigned short* const ringl0 = ring + l16 * 64 + swz0 * 8;       // ring bases
  unsigned short* const ringl1 = ring + l16 * 64 + (swz0 ^ 1) * 8;
  const int row0 = tid >> 3,          part0 = (tid & 7) ^ (row0 & 7);
  const int row1 = (tid + 256) >> 3,  part1 = (tid & 7) ^ (row1 & 7);
  const int soff0 = row0 * 256 + part0 * 4;   // stage src f32-elem offsets
  const int soff1 = row1 * 256 + part1 * 4;
  unsigned short* const sdst0 = ring + tid * 8;
  unsigned short* const sdst1 = ring + (tid + 256) * 8;
  const float* const gemoB  = gemo  + R0 * 256;
  const float* const colorB = color + R0 * 256;

  f32x4 acc[4][4];

  auto ldA2 = [&](const unsigned short* __restrict__ chunk, int ct) -> bf16x8 {
    return *(const bf16x8*)(chunk + wlane + ct * 512);       // imm ct*1024B
  };
  auto stageB = [&](const float* __restrict__ Pb, int slot, int c) {
    GLDS16(Pb + c * 32 + soff0, sdst0 + slot * 4096);
    GLDS16(Pb + c * 32 + soff1, sdst1 + slot * 4096);
  };
  auto ldR = [&](unsigned short* base, int slot, int rt) -> f32x4 {
    return *(const f32x4*)(base + slot * 4096 + rt * 1024);  // imm slot*8K+rt*2K
  };
  auto ldB_gen = [&](const float* __restrict__ p, int stride, int Kreal,
                     int rt, int ktl) -> bf16x8 {
    long row = R0 + rt * 16 + l16;
    const float* q = p + row * stride;
    int k0 = ktl * 32 + seg * 8;
    short8 s;
#pragma unroll
    for (int j = 0; j < 8; ++j) {
      float v = (k0 + j < Kreal) ? __builtin_nontemporal_load(q + k0 + j) : 0.0f;
      s[j] = (short)f2bf(v);
    }
    return as_bf(s);
  };
  auto initAcc = [&](const float* __restrict__ b) {
#pragma unroll
    for (int ct = 0; ct < 4; ++ct) {
      float4 bv = *(const float4*)(b + chb + ct * 16 + seg * 4);
      f32x4 t; t[0] = bv.x; t[1] = bv.y; t[2] = bv.z; t[3] = bv.w;
#pragma unroll
      for (int rt = 0; rt < 4; ++rt) acc[ct][rt] = t;
    }
  };
  auto storeAct = [&]() {
#pragma unroll
    for (int ct = 0; ct < 4; ++ct)
#pragma unroll
      for (int rt = 0; rt < 4; ++rt) {
        f32x4 v = acc[ct][rt];
        uint2 u;
        u.x = cvt_pk(fmaxf(v[0], 0.f), fmaxf(v[1], 0.f));
        u.y = cvt_pk(fmaxf(v[2], 0.f), fmaxf(v[3], 0.f));
        *(uint2*)(actw + rt * (16 * RS) + ct * 16) = u;      // imm rt*8320+ct*32
      }
  };

#define MFMA16(AFRAG, BFRAGS)                                                  \
  _Pragma("unroll") for (int ct = 0; ct < 4; ++ct) {                           \
    _Pragma("unroll") for (int rt = 0; rt < 4; ++rt)                           \
      acc[ct][rt] = __builtin_amdgcn_mfma_f32_16x16x32_bf16(                   \
          AFRAG[ct], BFRAGS[rt], acc[ct][rt], 0, 0, 0);                        \
  }

// 8 K-steps, B from act LDS (static imm addressing), A via uniform chunk ptr.
#define LHALF(WBASE)                                                           \
  _Pragma("unroll") for (int i = 0; i < 8; ++i) {                              \
    const unsigned short* ch_ = (WBASE) + i * 8192;                            \
    bf16x8 Bf_[4];                                                             \
    _Pragma("unroll") for (int rt = 0; rt < 4; ++rt)                           \
      Bf_[rt] = *(const bf16x8*)(actl + rt * (16 * RS) + i * 32);              \
    bf16x8 Af_[4];                                                             \
    _Pragma("unroll") for (int ct = 0; ct < 4; ++ct) Af_[ct] = ldA2(ch_, ct);  \
    MFMA16(Af_, Bf_);                                                          \
  }

// One stream step, 2-slot ring, AfG depth-2 (semantics = R11's GREG):
// [FENCE(4)][bar][stage c(i+1) + AfG(i+1)][ring-read + cvt][MFMA(i)]
// Ledger: at fence, outstanding = stage c(i) (2, oldest) + AfG(i) (4);
// FENCE(4) drains exactly stage c(i) -> slot i&1 ready. AfG(i) retired by
// the MFMA's compiler-auto wait. Stage-after-barrier is race-free (barrier
// certifies all reads of that slot's previous chunk were consumed by MFMA).
#define GREG(i)                                                                \
  {                                                                            \
    asm volatile("s_waitcnt vmcnt(4)" ::: "memory"); SB;                       \
    __builtin_amdgcn_s_barrier(); SB;                                          \
    if ((i) + 1 < 8) {                                                         \
      int cn = ((i) + 1 + rot) & 7;                                            \
      stageB(GP, ((i) + 1) & 1, cn);                                           \
      const unsigned short* chn_ = GW + (8 + cn) * 8192;                       \
      AfG[((i) + 1) & 1][0] = ldA2(chn_, 0);                                   \
      AfG[((i) + 1) & 1][1] = ldA2(chn_, 1);                                   \
      AfG[((i) + 1) & 1][2] = ldA2(chn_, 2);                                   \
      AfG[((i) + 1) & 1][3] = ldA2(chn_, 3);                                   \
    }                                                                          \
    SB;                                                                        \
    bf16x8 Bf_[4];                                                             \
    _Pragma("unroll") for (int rt = 0; rt < 4; ++rt) {                         \
      f32x4 lo = ldR(ringl0, (i) & 1, rt);                                     \
      f32x4 hi = ldR(ringl1, (i) & 1, rt);                                     \
      Bf_[rt] = cvt8(lo, hi);                                                  \
    }                                                                          \
    MFMA16(AfG[(i) & 1], Bf_);                                                 \
  }

#define GHALF(WBASE, PB)                                                       \
  {                                                                            \
    const unsigned short* GW = (WBASE);                                        \
    const float* __restrict__ GP = (PB);                                       \
    bf16x8 AfG[2][4];                                                          \
    SB;                                                                        \
    { const unsigned short* ch_ = GW + (8 + (rot & 7)) * 8192;                 \
      AfG[0][0] = ldA2(ch_, 0); AfG[0][1] = ldA2(ch_, 1);                      \
      AfG[0][2] = ldA2(ch_, 2); AfG[0][3] = ldA2(ch_, 3); }                    \
    SB;                                                                        \
    GREG(0) GREG(1) GREG(2) GREG(3)                                            \
    GREG(4) GREG(5) GREG(6) GREG(7)                                            \
  }

  // ---- L0: d0 = relu(pos @ W0 + b0) -> act
  initAcc(b0);
#pragma unroll
  for (int kt = 0; kt < 2; ++kt) {
    const unsigned short* ch0 = wp + P0B + kt * 8192;
    bf16x8 Bf_[4];
#pragma unroll
    for (int rt = 0; rt < 4; ++rt) Bf_[rt] = ldB_gen(pos, 63, 63, rt, kt);
    bf16x8 Af_[4];
#pragma unroll
    for (int ct = 0; ct < 4; ++ct) Af_[ct] = ldA2(ch0, ct);
    MFMA16(Af_, Bf_);
  }
  storeAct();
  __syncthreads();

  // ---- L1: d1 = relu(d0 @ W1 + b1); act: d0 -> d1
  initAcc(b1);
  LHALF(wp + P1B);
  __syncthreads();
  storeAct();
  __syncthreads();

  // ---- L2: d2 = [d1|gemo] @ W2 + b2 (stays in acc)
  SB; stageB(gemoB, 0, rot & 7); SB;   // c0 flies across LHALF's 8 steps
  initAcc(b2);
  LHALF(wp + P2B);
  GHALF(wp + P2B, gemoB);

  // ---- sigma head (in-register): softplus(relu(d2) @ Ws + bs) * mask
  {
    float p[4];
#pragma unroll
    for (int rt = 0; rt < 4; ++rt) {
      float s = 0.f;
#pragma unroll
      for (int ct = 0; ct < 4; ++ct) {
        float4 w4 = *(const float4*)(Wsf + chb + ct * 16 + seg * 4);
        f32x4 a = acc[ct][rt];
        s += fmaxf(a[0], 0.f) * w4.x + fmaxf(a[1], 0.f) * w4.y +
             fmaxf(a[2], 0.f) * w4.z + fmaxf(a[3], 0.f) * w4.w;
      }
      s += __shfl_xor(s, 16);
      s += __shfl_xor(s, 32);
      p[rt] = s;
    }
    if (seg == 0) {
#pragma unroll
      for (int rt = 0; rt < 4; ++rt) scr[w * 64 + rt * 16 + l16] = p[rt];
    }
  }
  __syncthreads();
  if (tid < 64) {
    float s = scr[tid] + scr[64 + tid] + scr[128 + tid] + scr[192 + tid] + bsv[0];
    float sp = fmaxf(s, 0.f) + log1pf(expf(-fabsf(s)));
    float m = __builtin_nontemporal_load(mask + R0 + tid);
    __builtin_nontemporal_store(sp * m, osig + R0 + tid);
  }

  // ---- L3: d3 = relu([d1|color] @ W3 + b3); act: d1 -> d3
  SB; stageB(colorB, 0, rot & 7); SB;  // c0 flies across LHALF's 8 steps
  initAcc(b3);
  LHALF(wp + P3B);
  GHALF(wp + P3B, colorB);
  __syncthreads();
  storeAct();
  __syncthreads();

  // ---- L4: d4 = [d3|dir|app] @ W4 + b4' (stays in acc)
  initAcc(b4p);
  LHALF(wp + P4AB);
  {  // dir step (K=32, direct A)
    const unsigned short* ch4 = wp + P4BB;
    bf16x8 Bf_[4];
#pragma unroll
    for (int rt = 0; rt < 4; ++rt) Bf_[rt] = ldB_gen(dirs, 27, 27, rt, 0);
    bf16x8 Af_[4];
#pragma unroll
    for (int ct = 0; ct < 4; ++ct) Af_[ct] = ldA2(ch4, ct);
    MFMA16(Af_, Bf_);
  }

  // ---- rgb head (in-register): sigmoid(relu(d4) @ Wr + br)
  {
#pragma unroll
    for (int ct = 0; ct < 4; ++ct)
#pragma unroll
      for (int rt = 0; rt < 4; ++rt) {
        f32x4 a = acc[ct][rt];
        a[0] = fmaxf(a[0], 0.f); a[1] = fmaxf(a[1], 0.f);
        a[2] = fmaxf(a[2], 0.f); a[3] = fmaxf(a[3], 0.f);
        acc[ct][rt] = a;
      }
#pragma unroll
    for (int c = 0; c < 3; ++c) {
      float p[4];
#pragma unroll
      for (int rt = 0; rt < 4; ++rt) {
        float s = 0.f;
#pragma unroll
        for (int ct = 0; ct < 4; ++ct) {
          float4 w4 = *(const float4*)(wrT + c * 256 + chb + ct * 16 + seg * 4);
          f32x4 a = acc[ct][rt];
          s += a[0] * w4.x + a[1] * w4.y + a[2] * w4.z + a[3] * w4.w;
        }
        s += __shfl_xor(s, 16);
        s += __shfl_xor(s, 32);
        p[rt] = s;
      }
      if (seg == 0) {
#pragma unroll
        for (int rt = 0; rt < 4; ++rt)
          scr[c * 256 + w * 64 + rt * 16 + l16] = p[rt];
      }
    }
  }
  __syncthreads();
  if (tid < 64) {
#pragma unroll
    for (int c = 0; c < 3; ++c) {
      float s = scr[c * 256 + tid] + scr[c * 256 + 64 + tid] +
                scr[c * 256 + 128 + tid] + scr[c * 256 + 192 + tid] + brv[c];
      float r = 1.f / (1.f + expf(-s));
      __builtin_nontemporal_store(r, orgb + (R0 + tid) * 3 + c);
    }
  }
#undef MFMA16
#undef LHALF
#undef GREG
#undef GHALF
}

extern "C" void kernel_launch(void* const* d_in, const int* in_sizes, int n_in,
                              void* d_out, int out_size, void* d_ws, size_t ws_size,
                              hipStream_t stream) {
  const float* pos   = (const float*)d_in[0];
  const float* dirs  = (const float*)d_in[1];
  const float* app   = (const float*)d_in[2];
  const float* gemo  = (const float*)d_in[3];
  const float* color = (const float*)d_in[4];
  const float* mask  = (const float*)d_in[5];
  // d_in[6] = num_inters (fixed 32, shapes are static)
  const float* W0 = (const float*)d_in[7];   const float* b0 = (const float*)d_in[8];
  const float* W1 = (const float*)d_in[9];   const float* b1 = (const float*)d_in[10];
  const float* W2 = (const float*)d_in[11];  const float* b2 = (const float*)d_in[12];
  const float* Ws = (const float*)d_in[13];  const float* bs = (const float*)d_in[14];
  const float* W3 = (const float*)d_in[15];  const float* b3 = (const float*)d_in[16];
  const float* W4 = (const float*)d_in[17];  const float* b4 = (const float*)d_in[18];
  const float* Wr = (const float*)d_in[19];  const float* br = (const float*)d_in[20];

  unsigned short* pack = (unsigned short*)d_ws;
  float* b4p = (float*)((char*)d_ws + (size_t)PTOT * 2);
  float* wrT = b4p + 256;

  float* osig = (float*)d_out;
  float* orgb = osig + NROWS;

  prep_pack<<<dim3((PTOT + 256 + 768 + 255) / 256), dim3(256), 0, stream>>>(
      W0, W1, W2, W3, W4, Wr, app, b4, pack, b4p, wrT);

  hipFuncSetAttribute((const void*)nerf_fused,
                      hipFuncAttributeMaxDynamicSharedMemorySize, SMEM_BYTES);

  nerf_fused<<<dim3(NROWS / MT), dim3(256), SMEM_BYTES, stream>>>(
      pos, dirs, gemo, color, mask, pack,
      b0, b1, b2, bs, b3, b4p, br, Ws, wrT, osig, orgb);
}